// Round 1
// baseline (1025.856 us; speedup 1.0000x reference)
//
#include <hip/hip_runtime.h>
#include <stdint.h>

typedef unsigned short u16;
typedef __bf16 bf16x8 __attribute__((ext_vector_type(8)));
typedef float f32x4 __attribute__((ext_vector_type(4)));

#define NMAP 131072
#define NACT 1024
#define NEDGE 262144

__device__ __forceinline__ u16 f2bf(float f) {
    union { float f; unsigned u; } v; v.f = f;
    unsigned r = v.u + 0x7fffu + ((v.u >> 16) & 1u);
    return (u16)(r >> 16);
}
__device__ __forceinline__ float bf2f(u16 h) {
    union { unsigned u; float f; } v; v.u = ((unsigned)h) << 16; return v.f;
}
__device__ __forceinline__ bf16x8 as_frag(uint4 u) {
    union { uint4 u; bf16x8 b; } v; v.u = u; return v.b;
}
__device__ __forceinline__ bf16x8 ldg_frag(const u16* p) {
    return as_frag(*reinterpret_cast<const uint4*>(p));
}
// LDS A-fragment read, XOR-swizzled rows (row-major, rowBytes per row)
__device__ __forceinline__ bf16x8 lds_frag(const u16* base, int rowBytes, int row, int k, int q4) {
    int off = row * rowBytes + (((k * 64) + q4 * 16) ^ ((row & 7) << 4));
    return as_frag(*reinterpret_cast<const uint4*>(base + (off >> 1)));
}

// C += X(16 rows, regs a[], K=KT*32) @ W[128][ldw]^T  for 8 col-tiles
template <int KT>
__device__ __forceinline__ void gemm_acc(const bf16x8* a, const u16* __restrict__ W, int ldw,
                                         f32x4* acc, int c16, int q4) {
#pragma unroll
    for (int n = 0; n < 8; n++) {
        const u16* wp = W + (size_t)(n * 16 + c16) * ldw + q4 * 8;
#pragma unroll
        for (int k = 0; k < KT; k++) {
            bf16x8 b = ldg_frag(wp + k * 32);
            acc[n] = __builtin_amdgcn_mfma_f32_16x16x32_bf16(a[k], b, acc[n], 0, 0, 0);
        }
    }
}

// GroupNorm(1,128) on C-layout acc[n][r]: row=(q4*4+r), col=n*16+c16
__device__ __forceinline__ void gn_c(f32x4* acc, const float* __restrict__ g,
                                     const float* __restrict__ b, bool relu, int c16) {
    float gs[8], bs[8];
#pragma unroll
    for (int n = 0; n < 8; n++) { gs[n] = g[n * 16 + c16]; bs[n] = b[n * 16 + c16]; }
#pragma unroll
    for (int r = 0; r < 4; r++) {
        float s = 0.f, s2 = 0.f;
#pragma unroll
        for (int n = 0; n < 8; n++) { float x = acc[n][r]; s += x; s2 = fmaf(x, x, s2); }
#pragma unroll
        for (int m = 1; m < 16; m <<= 1) { s += __shfl_xor(s, m, 64); s2 += __shfl_xor(s2, m, 64); }
        float mean = s * (1.f / 128.f);
        float var = fmaf(s2, 1.f / 128.f, -mean * mean);
        float rstd = rsqrtf(var + 1e-5f);
#pragma unroll
        for (int n = 0; n < 8; n++) {
            float y = fmaf((acc[n][r] - mean) * rstd, gs[n], bs[n]);
            acc[n][r] = relu ? fmaxf(y, 0.f) : y;
        }
    }
}

// ---------------- prep: f32 -> bf16 weight conversion + small repacks ----------------
__global__ __launch_bounds__(256) void k_prep(
    const float* __restrict__ dW2s, const float* __restrict__ qWs, const float* __restrict__ cW1s,
    const float* __restrict__ cW2s, const float* __restrict__ aWs, const float* __restrict__ lWs,
    const float* __restrict__ actors, const float* __restrict__ metaW,
    const float* __restrict__ dW1s, const float* __restrict__ db1s,
    u16* __restrict__ o_dW2, u16* __restrict__ o_qW, u16* __restrict__ o_cW1,
    u16* __restrict__ o_cW2, u16* __restrict__ o_aW, u16* __restrict__ o_lW,
    u16* __restrict__ o_actb, u16* __restrict__ o_mWf, float* __restrict__ o_mWe,
    float* __restrict__ o_dw1p) {
    int idx = blockIdx.x * 256 + threadIdx.x;
    if (idx >= 411136) return;
    if (idx < 32768) { o_dW2[idx] = f2bf(dW2s[idx]); }
    else if (idx < 65536) { int j = idx - 32768; o_qW[j] = f2bf(qWs[j]); }
    else if (idx < 163840) { int j = idx - 65536; o_cW1[j] = f2bf(cW1s[j]); }
    else if (idx < 196608) { int j = idx - 163840; o_cW2[j] = f2bf(cW2s[j]); }
    else if (idx < 229376) { int j = idx - 196608; o_aW[j] = f2bf(aWs[j]); }
    else if (idx < 262144) { int j = idx - 229376; o_lW[j] = f2bf(lWs[j]); }
    else if (idx < 393216) { int j = idx - 262144; o_actb[j] = f2bf(actors[j]); }
    else if (idx < 409600) { int j = idx - 393216; o_mWf[j] = f2bf(metaW[(j >> 7) * 132 + (j & 127)]); }
    else if (idx < 410112) { int j = idx - 409600; o_mWe[j] = metaW[(j >> 2) * 132 + 128 + (j & 3)]; }
    else {
        int j = idx - 410112; int i = j >> 9, col = (j >> 2) & 127, t = j & 3;
        float v = (t == 0) ? dW1s[i * 256 + col * 2]
                : (t == 1) ? dW1s[i * 256 + col * 2 + 1]
                : (t == 2) ? db1s[i * 128 + col] : 0.f;
        o_dw1p[j] = v;
    }
}

// ---------------- meta: feat = relu(GN(concat(feat,turn,ctrl,inter) @ mW^T)) ----------------
__global__ __launch_bounds__(256) void k_meta(
    const float* __restrict__ feat, const float* __restrict__ turn,
    const float* __restrict__ ctrl, const float* __restrict__ inter,
    const u16* __restrict__ mWf, const float* __restrict__ mWe,
    const float* __restrict__ g, const float* __restrict__ b, u16* __restrict__ out) {
    int lane = threadIdx.x & 63, wv = threadIdx.x >> 6;
    int c16 = lane & 15, q4 = lane >> 4;
    int m0 = (blockIdx.x * 4 + wv) * 16;
    bf16x8 a[4];
    const float* xr = feat + (size_t)(m0 + c16) * 128 + q4 * 8;
#pragma unroll
    for (int k = 0; k < 4; k++) {
        float4 u0 = *reinterpret_cast<const float4*>(xr + k * 32);
        float4 u1 = *reinterpret_cast<const float4*>(xr + k * 32 + 4);
        union { u16 s[8]; bf16x8 b; } t;
        t.s[0] = f2bf(u0.x); t.s[1] = f2bf(u0.y); t.s[2] = f2bf(u0.z); t.s[3] = f2bf(u0.w);
        t.s[4] = f2bf(u1.x); t.s[5] = f2bf(u1.y); t.s[6] = f2bf(u1.z); t.s[7] = f2bf(u1.w);
        a[k] = t.b;
    }
    f32x4 acc[8] = {};
    gemm_acc<4>(a, mWf, 128, acc, c16, q4);
#pragma unroll
    for (int r = 0; r < 4; r++) {
        int row = m0 + q4 * 4 + r;
        float t0 = turn[2 * row], t1 = turn[2 * row + 1];
        float cv = ctrl[row], iv = inter[row];
#pragma unroll
        for (int n = 0; n < 8; n++) {
            int col = n * 16 + c16;
            float4 we = reinterpret_cast<const float4*>(mWe)[col];
            acc[n][r] += t0 * we.x + t1 * we.y + cv * we.z + iv * we.w;
        }
    }
    gn_c(acc, g, b, true, c16);
#pragma unroll
    for (int r = 0; r < 4; r++) {
        size_t row = m0 + q4 * 4 + r;
#pragma unroll
        for (int n = 0; n < 8; n++) out[row * 128 + n * 16 + c16] = f2bf(acc[n][r]);
    }
}

// ---------------- nodeA: q_node = relu(GN(feat@qW^T)); a = feat@aW^T ----------------
__global__ __launch_bounds__(256) void k_nodeA(
    const u16* __restrict__ featb, const u16* __restrict__ qW, const u16* __restrict__ aW,
    const float* __restrict__ qg, const float* __restrict__ qb,
    u16* __restrict__ q_out, float* __restrict__ a_out) {
    int lane = threadIdx.x & 63, wv = threadIdx.x >> 6;
    int c16 = lane & 15, q4 = lane >> 4;
    int m0 = (blockIdx.x * 4 + wv) * 16;
    bf16x8 a[4];
    const u16* xr = featb + (size_t)(m0 + c16) * 128 + q4 * 8;
#pragma unroll
    for (int k = 0; k < 4; k++) a[k] = ldg_frag(xr + k * 32);
    f32x4 accq[8] = {}, acca[8] = {};
    gemm_acc<4>(a, qW, 128, accq, c16, q4);
    gemm_acc<4>(a, aW, 128, acca, c16, q4);
#pragma unroll
    for (int r = 0; r < 4; r++) {
        size_t row = m0 + q4 * 4 + r;
#pragma unroll
        for (int n = 0; n < 8; n++) a_out[row * 128 + n * 16 + c16] = acca[n][r];
    }
    gn_c(accq, qg, qb, true, c16);
#pragma unroll
    for (int r = 0; r < 4; r++) {
        size_t row = m0 + q4 * 4 + r;
#pragma unroll
        for (int n = 0; n < 8; n++) q_out[row * 128 + n * 16 + c16] = f2bf(accq[n][r]);
    }
}

// ---------------- edge: fused dist->concat->cW1->cW2 -> atomic scatter ----------------
__global__ __launch_bounds__(256) void k_edge(
    const int* __restrict__ hi, const int* __restrict__ wi,
    const float* __restrict__ mctr, const float* __restrict__ actr,
    const float* __restrict__ dw1p, const u16* __restrict__ dW2,
    const float* __restrict__ dg2, const float* __restrict__ dbt2,
    const u16* __restrict__ q_node, const u16* __restrict__ actb,
    const u16* __restrict__ cW1, const float* __restrict__ cg1, const float* __restrict__ cb1,
    const u16* __restrict__ cW2, float* __restrict__ a_out) {
    __shared__ u16 sb1[4][16 * 128];
    __shared__ u16 sb2[4][16 * 384];
    int lane = threadIdx.x & 63, wv = threadIdx.x >> 6;
    int c16 = lane & 15, q4 = lane >> 4;
    int m0 = (blockIdx.x * 4 + wv) * 16;
    u16* B1 = sb1[wv];
    u16* B2 = sb2[wv];
    int e = m0 + c16;
    int h = hi[e], w = wi[e];
    float d0x = mctr[2 * h] - actr[2 * w];
    float d0y = mctr[2 * h + 1] - actr[2 * w + 1];
    // d1 = relu(d0 @ dW1^T + db1) -> B1 (row c16, cols q4*32..+32)
#pragma unroll
    for (int j = 0; j < 4; j++) {
        union { u16 s[8]; uint4 u; } t;
#pragma unroll
        for (int tt = 0; tt < 8; tt++) {
            int col = q4 * 32 + j * 8 + tt;
            float4 w4 = reinterpret_cast<const float4*>(dw1p)[col];
            t.s[tt] = f2bf(fmaxf(fmaf(d0x, w4.x, fmaf(d0y, w4.y, w4.z)), 0.f));
        }
        int off = (q4 * 64 + j * 16) ^ ((c16 & 7) << 4);
        *reinterpret_cast<uint4*>(&B1[(c16 * 256 + off) >> 1]) = t.u;
    }
    __syncthreads();
    bf16x8 a1[4];
#pragma unroll
    for (int k = 0; k < 4; k++) a1[k] = lds_frag(B1, 256, c16, k, q4);
    f32x4 acc1[8] = {};
    gemm_acc<4>(a1, dW2, 128, acc1, c16, q4);
    gn_c(acc1, dg2, dbt2, true, c16);
    // d2 -> concat cols [0,128)
#pragma unroll
    for (int r = 0; r < 4; r++) {
        int row = q4 * 4 + r;
#pragma unroll
        for (int n = 0; n < 8; n++)
            B2[(row * 768 + ((n * 32 + c16 * 2) ^ ((row & 7) << 4))) >> 1] = f2bf(acc1[n][r]);
    }
    // gather q_node[hi] -> cols [128,256), actors[wi] -> cols [256,384)
#pragma unroll
    for (int j = 0; j < 4; j++) {
        int chunk = q4 * 4 + j;
        uint4 v1 = *reinterpret_cast<const uint4*>(q_node + (size_t)h * 128 + chunk * 8);
        *reinterpret_cast<uint4*>(&B2[(c16 * 768 + ((256 + chunk * 16) ^ ((c16 & 7) << 4))) >> 1]) = v1;
        uint4 v2 = *reinterpret_cast<const uint4*>(actb + (size_t)w * 128 + chunk * 8);
        *reinterpret_cast<uint4*>(&B2[(c16 * 768 + ((512 + chunk * 16) ^ ((c16 & 7) << 4))) >> 1]) = v2;
    }
    __syncthreads();
    bf16x8 a2[12];
#pragma unroll
    for (int k = 0; k < 12; k++) a2[k] = lds_frag(B2, 768, c16, k, q4);
    f32x4 acc2[8] = {};
    gemm_acc<12>(a2, cW1, 384, acc2, c16, q4);
    gn_c(acc2, cg1, cb1, true, c16);
    __syncthreads();
#pragma unroll
    for (int r = 0; r < 4; r++) {
        int row = q4 * 4 + r;
#pragma unroll
        for (int n = 0; n < 8; n++)
            B1[(row * 256 + ((n * 32 + c16 * 2) ^ ((row & 7) << 4))) >> 1] = f2bf(acc2[n][r]);
    }
    __syncthreads();
    bf16x8 a3[4];
#pragma unroll
    for (int k = 0; k < 4; k++) a3[k] = lds_frag(B1, 256, c16, k, q4);
    f32x4 acc3[8] = {};
    gemm_acc<4>(a3, cW2, 128, acc3, c16, q4);
#pragma unroll
    for (int r = 0; r < 4; r++) {
        int hr = hi[m0 + q4 * 4 + r];
        float* dst = a_out + (size_t)hr * 128 + c16;
#pragma unroll
        for (int n = 0; n < 8; n++) unsafeAtomicAdd(dst + n * 16, acc3[n][r]);
    }
}

// ---------------- nodeB: a=relu(GN(a)); a2=GN(a@lW^T); feat=relu(a2+res) ----------------
__global__ __launch_bounds__(256) void k_nodeB(
    const float* __restrict__ a_in, const float* __restrict__ gg, const float* __restrict__ gb,
    const u16* __restrict__ lW, const float* __restrict__ lg, const float* __restrict__ lb,
    const u16* __restrict__ res, u16* __restrict__ out_bf, float* __restrict__ out_f32) {
    int lane = threadIdx.x & 63, wv = threadIdx.x >> 6;
    int c16 = lane & 15, q4 = lane >> 4;
    int m0 = (blockIdx.x * 4 + wv) * 16;
    const float* xr = a_in + (size_t)(m0 + c16) * 128 + q4 * 8;
    float x[32];
#pragma unroll
    for (int k = 0; k < 4; k++) {
        float4 u0 = *reinterpret_cast<const float4*>(xr + k * 32);
        float4 u1 = *reinterpret_cast<const float4*>(xr + k * 32 + 4);
        x[k * 8 + 0] = u0.x; x[k * 8 + 1] = u0.y; x[k * 8 + 2] = u0.z; x[k * 8 + 3] = u0.w;
        x[k * 8 + 4] = u1.x; x[k * 8 + 5] = u1.y; x[k * 8 + 6] = u1.z; x[k * 8 + 7] = u1.w;
    }
    float s = 0.f, s2 = 0.f;
#pragma unroll
    for (int t = 0; t < 32; t++) { s += x[t]; s2 = fmaf(x[t], x[t], s2); }
    s += __shfl_xor(s, 16, 64); s += __shfl_xor(s, 32, 64);
    s2 += __shfl_xor(s2, 16, 64); s2 += __shfl_xor(s2, 32, 64);
    float mean = s * (1.f / 128.f);
    float var = fmaf(s2, 1.f / 128.f, -mean * mean);
    float rstd = rsqrtf(var + 1e-5f);
    bf16x8 a[4];
#pragma unroll
    for (int k = 0; k < 4; k++) {
        float4 g0 = *reinterpret_cast<const float4*>(gg + k * 32 + q4 * 8);
        float4 g1 = *reinterpret_cast<const float4*>(gg + k * 32 + q4 * 8 + 4);
        float4 b0 = *reinterpret_cast<const float4*>(gb + k * 32 + q4 * 8);
        float4 b1 = *reinterpret_cast<const float4*>(gb + k * 32 + q4 * 8 + 4);
        float gv[8] = {g0.x, g0.y, g0.z, g0.w, g1.x, g1.y, g1.z, g1.w};
        float bv[8] = {b0.x, b0.y, b0.z, b0.w, b1.x, b1.y, b1.z, b1.w};
        union { u16 s[8]; bf16x8 b; } t;
#pragma unroll
        for (int j = 0; j < 8; j++) {
            float y = fmaf((x[k * 8 + j] - mean) * rstd, gv[j], bv[j]);
            t.s[j] = f2bf(fmaxf(y, 0.f));
        }
        a[k] = t.b;
    }
    f32x4 acc[8] = {};
    gemm_acc<4>(a, lW, 128, acc, c16, q4);
    gn_c(acc, lg, lb, false, c16);
#pragma unroll
    for (int r = 0; r < 4; r++) {
        size_t row = m0 + q4 * 4 + r;
#pragma unroll
        for (int n = 0; n < 8; n++) {
            int col = n * 16 + c16;
            float y = acc[n][r] + bf2f(res[row * 128 + col]);
            y = fmaxf(y, 0.f);
            if (out_bf) out_bf[row * 128 + col] = f2bf(y);
            else out_f32[row * 128 + col] = y;
        }
    }
}

extern "C" void kernel_launch(void* const* d_in, const int* in_sizes, int n_in,
                              void* d_out, int out_size, void* d_ws, size_t ws_size,
                              hipStream_t stream) {
    const float* feat = (const float*)d_in[0];
    const float* turn = (const float*)d_in[1];
    const float* ctrl = (const float*)d_in[2];
    const float* inter = (const float*)d_in[3];
    const float* mctr = (const float*)d_in[4];
    const float* actors = (const float*)d_in[5];
    const float* actr = (const float*)d_in[6];
    const int* hi = (const int*)d_in[7];
    const int* wi = (const int*)d_in[8];
    const float* metaW = (const float*)d_in[9];
    const float* metag = (const float*)d_in[10];
    const float* metab = (const float*)d_in[11];
    const float* dW1 = (const float*)d_in[12];
    const float* db1 = (const float*)d_in[13];
    const float* dW2 = (const float*)d_in[14];
    const float* dg2 = (const float*)d_in[15];
    const float* dbt2 = (const float*)d_in[16];
    const float* qW = (const float*)d_in[17];
    const float* qg = (const float*)d_in[18];
    const float* qb = (const float*)d_in[19];
    const float* cW1 = (const float*)d_in[20];
    const float* cg1 = (const float*)d_in[21];
    const float* cb1 = (const float*)d_in[22];
    const float* cW2 = (const float*)d_in[23];
    const float* aW = (const float*)d_in[24];
    const float* ngg = (const float*)d_in[25];
    const float* ngb = (const float*)d_in[26];
    const float* lW = (const float*)d_in[27];
    const float* lg = (const float*)d_in[28];
    const float* lb = (const float*)d_in[29];

    char* ws = (char*)d_ws;
    u16* feat0 = (u16*)(ws);                    // 33554432 B
    u16* feat1 = (u16*)(ws + 33554432);         // 33554432 B
    u16* qbuf = (u16*)(ws + 67108864);          // 33554432 B
    u16* actb = (u16*)(ws + 100663296);         // 262144 B
    u16* wmWf = (u16*)(ws + 100925440);         // 32768 B
    u16* wdW2 = (u16*)(ws + 100958208);         // 65536 B
    u16* wqW = (u16*)(ws + 101023744);          // 65536 B
    u16* wcW1 = (u16*)(ws + 101089280);         // 196608 B
    u16* wcW2 = (u16*)(ws + 101285888);         // 65536 B
    u16* waW = (u16*)(ws + 101351424);          // 65536 B
    u16* wlW = (u16*)(ws + 101416960);          // 65536 B
    float* wmWe = (float*)(ws + 101482496);     // 2048 B
    float* wdw1p = (float*)(ws + 101484544);    // 4096 B
    float* abuf = (float*)d_out;                // reuse d_out as f32 scatter buffer

    k_prep<<<1606, 256, 0, stream>>>(dW2, qW, cW1, cW2, aW, lW, actors, metaW, dW1, db1,
                                     wdW2, wqW, wcW1, wcW2, waW, wlW, actb, wmWf, wmWe, wdw1p);
    k_meta<<<2048, 256, 0, stream>>>(feat, turn, ctrl, inter, wmWf, wmWe, metag, metab, feat0);
    for (int i = 0; i < 2; i++) {
        const u16* fcur = i ? feat1 : feat0;
        k_nodeA<<<2048, 256, 0, stream>>>(fcur, wqW + i * 16384, waW + i * 16384,
                                          qg + i * 128, qb + i * 128, qbuf, abuf);
        k_edge<<<4096, 256, 0, stream>>>(hi, wi, mctr, actr, wdw1p + i * 512, wdW2 + i * 16384,
                                         dg2 + i * 128, dbt2 + i * 128, qbuf, actb,
                                         wcW1 + i * 49152, cg1 + i * 128, cb1 + i * 128,
                                         wcW2 + i * 16384, abuf);
        k_nodeB<<<2048, 256, 0, stream>>>(abuf, ngg + i * 128, ngb + i * 128, wlW + i * 16384,
                                          lg + i * 128, lb + i * 128, fcur,
                                          i ? nullptr : feat1, i ? (float*)d_out : nullptr);
    }
}